// Round 4
// baseline (62.694 us; speedup 1.0000x reference)
//
#include <hip/hip_runtime.h>

#define S      4096
#define CIN    7
#define DM     512
#define KERN   73
#define TT     128
#define TILES  (S / TT)       // 32
#define NSTAGE (TT + 17)      // 145 valid staged elements per channel row
#define TROW   148            // row stride (16B aligned; covers overreads to j=147)
#define CHUNK  8

__global__ __launch_bounds__(512, 2)
void tokemb_kernel(const float* __restrict__ x,
                   const float* __restrict__ w_conv,
                   const float* __restrict__ b_conv,
                   const float* __restrict__ w_left,
                   const float* __restrict__ b_left,
                   float* __restrict__ out)
{
    __shared__ float xs[CIN * TROW];

    const int blk  = blockIdx.x;
    const int b    = blk >> 5;          // TILES = 32
    const int tile = blk & (TILES - 1);
    const int t0   = tile * TT;
    const int tid  = threadIdx.x;

    // ---- stage x tile into LDS transposed: xs[c][j] = x[b, (t0-16+j) mod S, c]
    // address is xb + 4*e (linear, coalesced) except at the wrap seam.
    const float* xb = x + (long long)b * S * CIN;
    for (int e = tid; e < CIN * NSTAGE; e += 512) {
        int j = e / CIN, c = e - j * CIN;
        int tm = t0 - 16 + j;
        if (tm < 0) tm += S; else if (tm >= S) tm -= S;
        xs[c * TROW + j] = xb[tm * CIN + c];
    }

    // ---- thread owns d-quad d0..d0+3 and a 32-t strip ----
    const int dq = tid & 127, d0 = 4 * dq;
    const int tg = tid >> 7;            // 0..3

    float g[4][18], bias[4];
    int   row[4];
    #pragma unroll
    for (int dd = 0; dd < 4; ++dd) {
        const int d  = d0 + dd;
        const int oo = d % KERN;
        const float* wrow = (d < DM - 1) ? (w_conv + oo * 18) : w_left;
        bias[dd] = (d < DM - 1) ? b_conv[oo] : b_left[0];
        row[dd]  = (d < DM - 1) ? (d / KERN) : (CIN - 1);
        // FIR tap order: off = 15 - 3m + k  ->  g[off] = wrow[(5-off/3)*3 + off%3]
        #pragma unroll
        for (int off = 0; off < 18; ++off)
            g[dd][off] = wrow[(5 - off / 3) * 3 + (off % 3)];
    }

    __syncthreads();

    const int tstart = t0 + tg * 32;
    const int jbase  = tg * 32;
    float* op = out + ((long long)b * S + tstart) * DM + d0;

    const bool edgeblk = (tile == 0 && tg == 0) || (tile == TILES - 1 && tg == 3);

    for (int ch = 0; ch < 32; ch += CHUNK) {
        float acc[4][CHUNK];
        const int tc = tstart + ch;
        const bool edge = edgeblk && ((tc < 16) || (tc + CHUNK >= S)); // wave-uniform

        if (!edge) {
            #pragma unroll
            for (int dd = 0; dd < 4; ++dd) {
                const float* xw = xs + row[dd] * TROW + jbase + ch;
                float w4[28];
                #pragma unroll
                for (int q = 0; q < 7; ++q) {
                    float4 v = *reinterpret_cast<const float4*>(xw + 4 * q);
                    w4[4*q+0] = v.x; w4[4*q+1] = v.y;
                    w4[4*q+2] = v.z; w4[4*q+3] = v.w;
                }
                #pragma unroll
                for (int i = 0; i < CHUNK; ++i) {
                    float a = bias[dd];
                    #pragma unroll
                    for (int off = 0; off < 18; ++off)
                        a = fmaf(g[dd][off], w4[i + off], a);
                    acc[dd][i] = a;
                }
            }
        } else {
            #pragma unroll
            for (int dd = 0; dd < 4; ++dd) {
                const float* xw = xs + row[dd] * TROW + jbase + ch;
                #pragma unroll
                for (int i = 0; i < CHUNK; ++i) {
                    float p0 = 0.f, p1 = 0.f, p2 = 0.f;
                    #pragma unroll
                    for (int o = 0; o < 18; o += 3) {
                        p0 = fmaf(g[dd][o],     xw[i + o],     p0);
                        p1 = fmaf(g[dd][o + 1], xw[i + o + 1], p1);
                        p2 = fmaf(g[dd][o + 2], xw[i + o + 2], p2);
                    }
                    const int t = tc + i;
                    const float f0 = (t == 0 || t >= 16)     ? 1.f : 0.f;
                    const float f1 = (t >= 15)               ? 1.f : 0.f;
                    const float f2 = (t >= 14 && t != S - 1) ? 1.f : 0.f;
                    acc[dd][i] = bias[dd] + f0 * p0 + f1 * p1 + f2 * p2;
                }
            }
        }

        #pragma unroll
        for (int i = 0; i < CHUNK; ++i) {
            float4 v = make_float4(acc[0][i], acc[1][i], acc[2][i], acc[3][i]);
            *reinterpret_cast<float4*>(op + (ch + i) * DM) = v;   // plain cached store
        }
    }
}

extern "C" void kernel_launch(void* const* d_in, const int* in_sizes, int n_in,
                              void* d_out, int out_size, void* d_ws, size_t ws_size,
                              hipStream_t stream) {
    const float* x      = (const float*)d_in[0];
    const float* w_conv = (const float*)d_in[1];
    const float* b_conv = (const float*)d_in[2];
    const float* w_left = (const float*)d_in[3];
    const float* b_left = (const float*)d_in[4];
    float* out = (float*)d_out;

    const int B = in_sizes[0] / (S * CIN);   // 32
    dim3 grid(B * TILES);
    tokemb_kernel<<<grid, 512, 0, stream>>>(x, w_conv, b_conv, w_left, b_left, out);
}